// Round 15
// baseline (194.039 us; speedup 1.0000x reference)
//
#include <hip/hip_runtime.h>
#include <stdint.h>

typedef unsigned short u16;
typedef __bf16 bf16_t;
typedef bf16_t bf16x8 __attribute__((ext_vector_type(8)));
typedef float f32x4 __attribute__((ext_vector_type(4)));

__device__ __forceinline__ u16 f2bf(float f) {
  union { float f; unsigned int u; } v; v.f = f;
  return (u16)((v.u + 0x7FFFu + ((v.u >> 16) & 1u)) >> 16);
}
__device__ __forceinline__ float bf2f(u16 b) {
  union { unsigned int u; float f; } v; v.u = ((unsigned int)b) << 16;
  return v.f;
}
__device__ __forceinline__ unsigned pk2bf(float a, float b) {
  return (unsigned)f2bf(a) | ((unsigned)f2bf(b) << 16);
}

#define MFMA16(a, b, c) __builtin_amdgcn_mfma_f32_16x16x32_bf16((a), (b), (c), 0, 0, 0)
#define GLL16(g, l) __builtin_amdgcn_global_load_lds( \
    (const __attribute__((address_space(1))) void*)(g), \
    (__attribute__((address_space(3))) void*)(l), 16, 0, 0)

// granule-XOR swizzle: permutes 8-u16 granules within a row; same formula on
// write and read -> bijective & self-consistent.
#define SWZ(row, col) ((col) ^ (((row) & 7) << 3))

#define SCALE 0.07216878364870323f      // 1/sqrt(3*64)
#define SCALE_L2E 0.10411754546752362f  // SCALE * log2(e)
#define LOG2E 1.4426950408889634f
#define M8L2E -11.541560327111707f      // -8 * log2(e)

// ---------------- fused prep: hs->bf16, rel->bf16, 5x W transpose ----------------
__global__ void prep(const float* __restrict__ hs, const float* __restrict__ rel,
                     const float* __restrict__ Wq, const float* __restrict__ Wk,
                     const float* __restrict__ Wv, const float* __restrict__ Wpk,
                     const float* __restrict__ Wpq,
                     u16* __restrict__ hsb, u16* __restrict__ relb,
                     u16* __restrict__ WqT, u16* __restrict__ WkT, u16* __restrict__ WvT,
                     u16* __restrict__ WpkT, u16* __restrict__ WpqT) {
  __shared__ float t[32][33];
  const int bid = blockIdx.x, tid = threadIdx.x;
  if (bid < 5121) {
    const float* in;
    u16* out;
    int i;
    if (bid < 4096) { in = hs; out = hsb; i = bid * 256 + tid; }
    else            { in = rel; out = relb; i = (bid - 4096) * 256 + tid; }
    float4 v = ((const float4*)in)[i];
    ushort4 o;
    o.x = f2bf(v.x); o.y = f2bf(v.y); o.z = f2bf(v.z); o.w = f2bf(v.w);
    ((ushort4*)out)[i] = o;
    return;
  }
  const int tt = bid - 5121;
  const int z = tt >> 10, rem = tt & 1023;
  const int x0 = (rem & 31) * 32, y0 = (rem >> 5) * 32;
  const float* in;
  u16* out;
  switch (z) {
    case 0: in = Wq; out = WqT; break;
    case 1: in = Wk; out = WkT; break;
    case 2: in = Wv; out = WvT; break;
    case 3: in = Wpk; out = WpkT; break;
    default: in = Wpq; out = WpqT; break;
  }
  int tx = tid & 31, ty = tid >> 5;
  #pragma unroll
  for (int i = ty; i < 32; i += 8)
    t[i][tx] = in[(size_t)(y0 + i) * 1024 + x0 + tx];
  __syncthreads();
  #pragma unroll
  for (int i = ty; i < 32; i += 8)
    out[(size_t)(x0 + i) * 1024 + y0 + tx] = f2bf(t[tx][i]);
}

// ---------------- merged 5-matrix bf16 GEMM (proven BK=32 body) ----------------
// One dispatch, 912 blocks with bijective XCD swizzle (912 = 8*114): each XCD
// gets a contiguous chunk of work ids -> shared B-panels stay in one L2.
// work id < 144 -> rel GEMMs (rk,rq; M=1025); else qkv GEMMs (q,k,v; M=4096).
// qkv mat 0,1 -> qout[(b*16+h)][s][d]; mat 2 -> qout[..][d][s] (transposed V,
// written via LDS-transpose epilogue for coalescing).
// rel mat -> rout + mat*1049600, layout [h][r][d].
__global__ void __launch_bounds__(256) gemm_all(
    const u16* __restrict__ hsb, const u16* __restrict__ relb,
    const u16* __restrict__ Wqkv, const u16* __restrict__ Wrel,
    const float* __restrict__ bq, const float* __restrict__ bk, const float* __restrict__ bv,
    const float* __restrict__ bpk, const float* __restrict__ bpq,
    u16* __restrict__ qout, u16* __restrict__ rout) {
  __shared__ __align__(16) u16 As[4096];
  __shared__ __align__(16) u16 Bs[4096];
  const int K = 1024;
  // XCD-bijective: hw block hid -> work id fid; XCD x serves fids [x*114,(x+1)*114)
  const int hid = blockIdx.x;
  const int fid = (hid & 7) * 114 + (hid >> 3);
  const u16* A;
  const u16* BTm;
  const float* bias;
  int m0, n0, mat, M, is_rel;
  if (fid < 144) {
    is_rel = 1;
    const int by = fid / 9;
    m0 = (fid % 9) * 128;
    n0 = (by & 7) * 128;
    mat = by >> 3;
    A = relb;
    BTm = Wrel + (size_t)mat * 1048576;
    bias = (mat == 0) ? bpk : bpq;
    M = 1025;
  } else {
    is_rel = 0;
    const int qid = fid - 144;
    const int by = qid >> 5;
    m0 = (qid & 31) * 128;
    n0 = (by & 7) * 128;
    mat = by >> 3;
    A = hsb;
    BTm = Wqkv + (size_t)mat * 1048576;
    bias = (mat == 0) ? bq : ((mat == 1) ? bk : bv);
    M = 4096;
  }
  const int w = threadIdx.x >> 6, lane = threadIdx.x & 63;
  const int lj = lane & 15, lg = lane >> 4;
  const int wm = (w >> 1) * 64, wn = (w & 1) * 64;

  f32x4 acc[4][4] = {};

  const int chunk0 = w * 128 + lane;
  const int chunk1 = chunk0 + 64;
  int r0 = chunk0 >> 2, s0 = (chunk0 & 3) * 8;
  int r1 = chunk1 >> 2, s1 = (chunk1 & 3) * 8;
  int ar0 = m0 + r0; if (ar0 >= M) ar0 = M - 1;
  int ar1 = m0 + r1; if (ar1 >= M) ar1 = M - 1;
  const u16* ga0 = A + (size_t)ar0 * K + s0;
  const u16* ga1 = A + (size_t)ar1 * K + s1;
  const u16* gb0 = BTm + (size_t)(n0 + r0) * K + s0;
  const u16* gb1 = BTm + (size_t)(n0 + r1) * K + s1;
  u16* lA0 = As + (w * 2 + 0) * 512;
  u16* lA1 = As + (w * 2 + 1) * 512;
  u16* lB0 = Bs + (w * 2 + 0) * 512;
  u16* lB1 = Bs + (w * 2 + 1) * 512;

  for (int k0 = 0; k0 < K; k0 += 32) {
    GLL16(ga0 + k0, lA0);
    GLL16(ga1 + k0, lA1);
    GLL16(gb0 + k0, lB0);
    GLL16(gb1 + k0, lB1);
    __syncthreads();
    bf16x8 af[4], bf8[4];
    #pragma unroll
    for (int mf = 0; mf < 4; ++mf)
      af[mf] = *(const bf16x8*)(As + (wm + mf * 16 + lj) * 32 + lg * 8);
    #pragma unroll
    for (int nf = 0; nf < 4; ++nf)
      bf8[nf] = *(const bf16x8*)(Bs + (wn + nf * 16 + lj) * 32 + lg * 8);
    #pragma unroll
    for (int mf = 0; mf < 4; ++mf)
      #pragma unroll
      for (int nf = 0; nf < 4; ++nf)
        acc[mf][nf] = MFMA16(af[mf], bf8[nf], acc[mf][nf]);
    __syncthreads();
  }

  if (is_rel) {
    #pragma unroll
    for (int mf = 0; mf < 4; ++mf)
      #pragma unroll
      for (int nf = 0; nf < 4; ++nf) {
        const int j = n0 + wn + nf * 16 + lj;
        const float bj = bias[j];
        #pragma unroll
        for (int r = 0; r < 4; ++r) {
          const int i = m0 + wm + mf * 16 + lg * 4 + r;
          if (i >= M) continue;
          rout[(size_t)mat * 1049600 + (size_t)(j >> 6) * 65600 + (size_t)i * 64 + (j & 63)] =
              f2bf(acc[mf][nf][r] + bj);
        }
      }
  } else if (mat < 2) {
    #pragma unroll
    for (int mf = 0; mf < 4; ++mf)
      #pragma unroll
      for (int nf = 0; nf < 4; ++nf) {
        const int j = n0 + wn + nf * 16 + lj;
        const float bj = bias[j];
        #pragma unroll
        for (int r = 0; r < 4; ++r) {
          const int i = m0 + wm + mf * 16 + lg * 4 + r;
          qout[(size_t)mat * 4194304 +
               (size_t)(((i >> 10) << 4) + (j >> 6)) * 65536 + (size_t)(i & 1023) * 64 + (j & 63)] =
              f2bf(acc[mf][nf][r] + bj);
        }
      }
  } else {
    // V: transpose each wave's 64(i)x16(j) subtile via LDS scratch, then
    // coalesced 16B global writes. As/Bs dead after final barrier; wave-private.
    u16* scr = (w < 2) ? (As + w * 1152) : (Bs + (w - 2) * 1152);
    u16* vout = qout + (size_t)2 * 4194304;
    const int row16 = lane >> 2, ch = lane & 3;
    #pragma unroll
    for (int nf = 0; nf < 4; ++nf) {
      const float bj = bias[n0 + wn + nf * 16 + lj];
      #pragma unroll
      for (int mf = 0; mf < 4; ++mf)
        #pragma unroll
        for (int r = 0; r < 4; ++r)
          scr[lj * 72 + mf * 16 + lg * 4 + r] = f2bf(acc[mf][nf][r] + bj);
      const u16* sp = scr + row16 * 72 + ch * 16;
      uint4 v0 = *(const uint4*)(sp);
      uint4 v1 = *(const uint4*)(sp + 8);
      const int gj = n0 + wn + nf * 16 + row16;
      const int gi = m0 + wm + ch * 16;
      u16* op = vout + (size_t)(((gi >> 10) << 4) + (gj >> 6)) * 65536 +
                (size_t)(gj & 63) * 1024 + (gi & 1023);
      *(uint4*)(op) = v0;
      *(uint4*)(op + 8) = v1;
    }
  }
}

// ---------------- fused disentangled attention (R11, unchanged) ----------------
__global__ void __launch_bounds__(256, 2) attn_fused(
    const u16* __restrict__ qg, const u16* __restrict__ kg, const u16* __restrict__ vtg,
    const u16* __restrict__ rkg, const u16* __restrict__ rqg,
    const float* __restrict__ mask, float* __restrict__ out) {
  __shared__ __align__(16) u16 Ks[64][64];     //  8192
  __shared__ __align__(16) u16 Ps[64][64];     //  8192
  __shared__ __align__(16) u16 RKs[128][64];   // 16384
  __shared__ __align__(16) u16 RQs[128][64];   // 16384
  __shared__ __align__(16) u16 Ts[64][128];    // 16384
  __shared__ __align__(16) u16 Us[64][128];    // 16384

  const int bx = ((blockIdx.x & 7) << 7) | (blockIdx.x >> 3);
  const int it = bx & 15, bn = bx >> 4;
  const int b = bn >> 4, n = bn & 15;
  const int i0 = it * 64;
  const int tid = threadIdx.x, w = tid >> 6, lane = tid & 63;
  const int lj = lane & 15, lg = lane >> 4;

  const u16* qh = qg + (size_t)bn * 65536;
  const u16* kh = kg + (size_t)bn * 65536;
  const u16* vth = vtg + (size_t)bn * 65536;
  const u16* rkh = rkg + (size_t)n * 65600;
  const u16* rqh = rqg + (size_t)n * 65600;
  const float* mk = mask + (size_t)b * 1024;

  const int l8 = lane >> 3, gK = (lane & 7) ^ l8;
  const u16* kb0  = kh  + (size_t)((w * 2 + 0) * 8 + l8) * 64 + gK * 8;
  const u16* kb1  = kh  + (size_t)((w * 2 + 1) * 8 + l8) * 64 + gK * 8;
  const u16* rkb0 = rkh + (size_t)((w * 4 + 0) * 8 + l8) * 64 + gK * 8;
  const u16* rkb1 = rkh + (size_t)((w * 4 + 1) * 8 + l8) * 64 + gK * 8;
  const u16* rkb2 = rkh + (size_t)((w * 4 + 2) * 8 + l8) * 64 + gK * 8;
  const u16* rkb3 = rkh + (size_t)((w * 4 + 3) * 8 + l8) * 64 + gK * 8;
  const u16* rqb0 = rqh + (size_t)((w * 4 + 0) * 8 + l8) * 64 + gK * 8;
  const u16* rqb1 = rqh + (size_t)((w * 4 + 1) * 8 + l8) * 64 + gK * 8;
  const u16* rqb2 = rqh + (size_t)((w * 4 + 2) * 8 + l8) * 64 + gK * 8;
  const u16* rqb3 = rqh + (size_t)((w * 4 + 3) * 8 + l8) * 64 + gK * 8;
  u16* ksd0 = &Ks[0][0]  + (w * 2 + 0) * 512;
  u16* ksd1 = &Ks[0][0]  + (w * 2 + 1) * 512;
  u16* rkd0 = &RKs[0][0] + (w * 4 + 0) * 512;
  u16* rkd1 = &RKs[0][0] + (w * 4 + 1) * 512;
  u16* rkd2 = &RKs[0][0] + (w * 4 + 2) * 512;
  u16* rkd3 = &RKs[0][0] + (w * 4 + 3) * 512;
  u16* rqd0 = &RQs[0][0] + (w * 4 + 0) * 512;
  u16* rqd1 = &RQs[0][0] + (w * 4 + 1) * 512;
  u16* rqd2 = &RQs[0][0] + (w * 4 + 2) * 512;
  u16* rqd3 = &RQs[0][0] + (w * 4 + 3) * 512;

#define STAGE_TILE(J0N) do { \
    const int ddn_ = i0 - (J0N) + 512; \
    int w0n_ = ddn_ - 63; w0n_ = w0n_ < 0 ? 0 : (w0n_ > 897 ? 897 : w0n_); \
    int w0qn_ = (1024 - ddn_) - 63; w0qn_ = w0qn_ < 0 ? 0 : (w0qn_ > 897 ? 897 : w0qn_); \
    GLL16(kb0 + (size_t)(J0N) * 64, ksd0); \
    GLL16(kb1 + (size_t)(J0N) * 64, ksd1); \
    GLL16(rkb0 + (size_t)w0n_ * 64, rkd0); \
    GLL16(rkb1 + (size_t)w0n_ * 64, rkd1); \
    GLL16(rkb2 + (size_t)w0n_ * 64, rkd2); \
    GLL16(rkb3 + (size_t)w0n_ * 64, rkd3); \
    GLL16(rqb0 + (size_t)w0qn_ * 64, rqd0); \
    GLL16(rqb1 + (size_t)w0qn_ * 64, rqd1); \
    GLL16(rqb2 + (size_t)w0qn_ * 64, rqd2); \
    GLL16(rqb3 + (size_t)w0qn_ * 64, rqd3); \
  } while (0)

  bf16x8 aq_all[4][2];
  #pragma unroll
  for (int f = 0; f < 4; ++f)
    #pragma unroll
    for (int k2 = 0; k2 < 2; ++k2)
      aq_all[f][k2] = *(const bf16x8*)(qh + (size_t)(i0 + f * 16 + lj) * 64 + k2 * 32 + lg * 8);
  bf16x8 aq_own[2];
  #pragma unroll
  for (int k2 = 0; k2 < 2; ++k2)
    aq_own[k2] = *(const bf16x8*)(qh + (size_t)(i0 + w * 16 + lj) * 64 + k2 * 32 + lg * 8);

  const u16* vrow[4];
  #pragma unroll
  for (int d = 0; d < 4; ++d)
    vrow[d] = vth + (size_t)(d * 16 + lj) * 1024 + lg * 8;

  const int swlj = (lj & 7) << 3;
  int baseT[4], swi[4], baseP[4];
  #pragma unroll
  for (int r = 0; r < 4; ++r) {
    const int il = w * 16 + lg * 4 + r;
    baseT[r] = il * 128;
    swi[r] = (il & 7) << 3;
    baseP[r] = il * 64;
  }
  const u16* Ts_f = &Ts[0][0];
  const u16* Us_f = &Us[0][0];
  u16* Ts_w = &Ts[0][0];
  u16* Us_w = &Us[0][0];
  u16* Ps_f = &Ps[0][0];

  float lsum[4] = {0.f, 0.f, 0.f, 0.f};
  f32x4 accO[4] = {};

  STAGE_TILE(0);

  for (int jt = 0; jt < 16; ++jt) {
    const int j0 = jt * 64;
    const int dd = i0 - j0 + 512;
    int w0 = dd - 63; w0 = w0 < 0 ? 0 : (w0 > 897 ? 897 : w0);
    int w0q = (1024 - dd) - 63; w0q = w0q < 0 ? 0 : (w0q > 897 ? 897 : w0q);

    __syncthreads();

    bf16x8 bk_all[4][2];
    #pragma unroll
    for (int f = 0; f < 4; ++f)
      #pragma unroll
      for (int k2 = 0; k2 < 2; ++k2) {
        const int kr = f * 16 + lj;
        bk_all[f][k2] = *(const bf16x8*)(&Ks[kr][SWZ(kr, k2 * 32 + lg * 8)]);
      }
    __builtin_amdgcn_s_setprio(1);
    f32x4 scc[4];
    #pragma unroll
    for (int jf = 0; jf < 4; ++jf) {
      scc[jf] = (f32x4){0.f, 0.f, 0.f, 0.f};
      #pragma unroll
      for (int k2 = 0; k2 < 2; ++k2)
        scc[jf] = MFMA16(aq_own[k2], bk_all[jf][k2], scc[jf]);
    }
    #pragma unroll
    for (int c16 = 0; c16 < 2; ++c16) {
      const int tc = w * 2 + c16;
      const int rr = tc * 16 + lj;
      bf16x8 brk[2], brq[2];
      #pragma unroll
      for (int k2 = 0; k2 < 2; ++k2) {
        brk[k2] = *(const bf16x8*)(&RKs[rr][SWZ(rr, k2 * 32 + lg * 8)]);
        brq[k2] = *(const bf16x8*)(&RQs[rr][SWZ(rr, k2 * 32 + lg * 8)]);
      }
      const int cb = (tc * 16 + lg * 4) ^ swlj;
      #pragma unroll
      for (int f = 0; f < 4; ++f) {
        f32x4 t_ = {0.f, 0.f, 0.f, 0.f};
        f32x4 u_ = {0.f, 0.f, 0.f, 0.f};
        #pragma unroll
        for (int k2 = 0; k2 < 2; ++k2) {
          t_ = MFMA16(brk[k2], aq_all[f][k2], t_);
          u_ = MFMA16(brq[k2], bk_all[f][k2], u_);
        }
        uint2 tp, up;
        tp.x = pk2bf(t_[0], t_[1]); tp.y = pk2bf(t_[2], t_[3]);
        up.x = pk2bf(u_[0], u_[1]); up.y = pk2bf(u_[2], u_[3]);
        *(uint2*)(Ts_w + (f * 16 + lj) * 128 + cb) = tp;
        *(uint2*)(Us_w + (f * 16 + lj) * 128 + cb) = up;
      }
    }
    __builtin_amdgcn_s_setprio(0);
    __syncthreads();

    if (jt < 15) STAGE_TILE(j0 + 64);

    bf16x8 vreg[8];
    #pragma unroll
    for (int jk = 0; jk < 2; ++jk)
      #pragma unroll
      for (int d = 0; d < 4; ++d)
        vreg[jk * 4 + d] = *(const bf16x8*)(vrow[d] + j0 + jk * 32);

    const int E = dd + w * 16 + lg * 4 - lj;
    const int C2 = 1024 - w0q;
    float mjs[4];
    #pragma unroll
    for (int jf = 0; jf < 4; ++jf)
      mjs[jf] = fmaf(mk[j0 + jf * 16 + lj], LOG2E, M8L2E);
    if (dd >= 63 && dd <= 961) {
      #pragma unroll
      for (int jf = 0; jf < 4; ++jf) {
        const int ubase = (jf * 16 + lj) * 128;
        #pragma unroll
        for (int r = 0; r < 4; ++r) {
          const int x1 = E + r - jf * 16;
          const float tT = bf2f(Ts_f[baseT[r] + ((x1 - w0) ^ swi[r])]);
          const float tU = bf2f(Us_f[ubase + ((C2 - x1) ^ swlj)]);
          const float p = __builtin_amdgcn_exp2f(
              fmaf(scc[jf][r] + tT + tU, SCALE_L2E, mjs[jf]));
          lsum[r] += p;
          Ps_f[baseP[r] + ((jf * 16 + lj) ^ (swi[r] & 56))] = f2bf(p);
        }
      }
    } else {
      #pragma unroll
      for (int jf = 0; jf < 4; ++jf) {
        const int ubase = (jf * 16 + lj) * 128;
        #pragma unroll
        for (int r = 0; r < 4; ++r) {
          int x1 = E + r - jf * 16;
          x1 = x1 < 0 ? 0 : (x1 > 1024 ? 1024 : x1);
          const float tT = bf2f(Ts_f[baseT[r] + ((x1 - w0) ^ swi[r])]);
          const float tU = bf2f(Us_f[ubase + ((C2 - x1) ^ swlj)]);
          const float p = __builtin_amdgcn_exp2f(
              fmaf(scc[jf][r] + tT + tU, SCALE_L2E, mjs[jf]));
          lsum[r] += p;
          Ps_f[baseP[r] + ((jf * 16 + lj) ^ (swi[r] & 56))] = f2bf(p);
        }
      }
    }
    __builtin_amdgcn_s_setprio(1);
    #pragma unroll
    for (int jk = 0; jk < 2; ++jk) {
      const int pr = w * 16 + lj;
      bf16x8 ap = *(const bf16x8*)(&Ps[pr][SWZ(pr, jk * 32 + lg * 8)]);
      #pragma unroll
      for (int d = 0; d < 4; ++d)
        accO[d] = MFMA16(ap, vreg[jk * 4 + d], accO[d]);
    }
    __builtin_amdgcn_s_setprio(0);
  }

  #pragma unroll
  for (int off = 1; off < 16; off <<= 1)
    #pragma unroll
    for (int r = 0; r < 4; ++r)
      lsum[r] += __shfl_xor(lsum[r], off);

  #pragma unroll
  for (int r = 0; r < 4; ++r) {
    const float inv = 1.f / lsum[r];
    const int i = i0 + w * 16 + lg * 4 + r;
    #pragma unroll
    for (int d = 0; d < 4; ++d)
      out[((size_t)b * 1024 + i) * 1024 + n * 64 + d * 16 + lj] = accO[d][r] * inv;
  }
#undef STAGE_TILE
}

extern "C" void kernel_launch(void* const* d_in, const int* in_sizes, int n_in,
                              void* d_out, int out_size, void* d_ws, size_t ws_size,
                              hipStream_t stream) {
  const float* hs   = (const float*)d_in[0];
  const float* mask = (const float*)d_in[1];
  const float* rel  = (const float*)d_in[2];
  const float* Wq   = (const float*)d_in[3];
  const float* bq   = (const float*)d_in[4];
  const float* Wk   = (const float*)d_in[5];
  const float* bk   = (const float*)d_in[6];
  const float* Wv   = (const float*)d_in[7];
  const float* bv   = (const float*)d_in[8];
  const float* Wpk  = (const float*)d_in[9];
  const float* bpk  = (const float*)d_in[10];
  const float* Wpq  = (const float*)d_in[11];
  const float* bpq  = (const float*)d_in[12];
  float* outp = (float*)d_out;

  u16* p = (u16*)d_ws;
  u16* hsb  = p; p += (size_t)4096 * 1024;
  u16* relb = p; p += (size_t)1025 * 1024;
  u16* WqT  = p; p += (size_t)1024 * 1024;   // WqT/WkT/WvT consecutive
  u16* WkT  = p; p += (size_t)1024 * 1024;
  u16* WvT  = p; p += (size_t)1024 * 1024;
  u16* WpkT = p; p += (size_t)1024 * 1024;   // WpkT/WpqT consecutive
  u16* WpqT = p; p += (size_t)1024 * 1024;
  u16* qws  = p; p += (size_t)4096 * 1024;   // q/k/v consecutive
  u16* kws  = p; p += (size_t)4096 * 1024;
  u16* vws  = p; p += (size_t)4096 * 1024;
  u16* rkws = p; p += (size_t)16 * 1025 * 64;  // rk/rq consecutive
  u16* rqws = p; p += (size_t)16 * 1025 * 64;
  if ((size_t)((char*)p - (char*)d_ws) > ws_size) return;  // ws too small: bail
  (void)kws; (void)rqws;

  prep<<<10241, 256, 0, stream>>>(hs, rel, Wq, Wk, Wv, Wpk, Wpq,
                                  hsb, relb, WqT, WkT, WvT, WpkT, WpqT);
  gemm_all<<<912, 256, 0, stream>>>(hsb, relb, WqT, WpkT,
                                    bq, bk, bv, bpk, bpq, qws, rkws);
  attn_fused<<<1024, 256, 0, stream>>>(qws, kws, vws, rkws, rqws, mask, outp);
}

// Round 16
// 193.043 us; speedup vs baseline: 1.0052x; 1.0052x over previous
//
#include <hip/hip_runtime.h>
#include <stdint.h>

typedef unsigned short u16;
typedef __bf16 bf16_t;
typedef bf16_t bf16x8 __attribute__((ext_vector_type(8)));
typedef float f32x4 __attribute__((ext_vector_type(4)));

__device__ __forceinline__ u16 f2bf(float f) {
  union { float f; unsigned int u; } v; v.f = f;
  return (u16)((v.u + 0x7FFFu + ((v.u >> 16) & 1u)) >> 16);
}
__device__ __forceinline__ float bf2f(u16 b) {
  union { unsigned int u; float f; } v; v.u = ((unsigned int)b) << 16;
  return v.f;
}
__device__ __forceinline__ unsigned pk2bf(float a, float b) {
  return (unsigned)f2bf(a) | ((unsigned)f2bf(b) << 16);
}

#define MFMA16(a, b, c) __builtin_amdgcn_mfma_f32_16x16x32_bf16((a), (b), (c), 0, 0, 0)
#define GLL16(g, l) __builtin_amdgcn_global_load_lds( \
    (const __attribute__((address_space(1))) void*)(g), \
    (__attribute__((address_space(3))) void*)(l), 16, 0, 0)

// granule-XOR swizzle: permutes 8-u16 granules within a row; same formula on
// write and read -> bijective & self-consistent.
#define SWZ(row, col) ((col) ^ (((row) & 7) << 3))

#define SCALE 0.07216878364870323f      // 1/sqrt(3*64)
#define SCALE_L2E 0.10411754546752362f  // SCALE * log2(e)
#define LOG2E 1.4426950408889634f
#define M8L2E -11.541560327111707f      // -8 * log2(e)

// ---------------- fused prep: hs->bf16, rel->bf16, 5x W transpose ----------------
__global__ void prep(const float* __restrict__ hs, const float* __restrict__ rel,
                     const float* __restrict__ Wq, const float* __restrict__ Wk,
                     const float* __restrict__ Wv, const float* __restrict__ Wpk,
                     const float* __restrict__ Wpq,
                     u16* __restrict__ hsb, u16* __restrict__ relb,
                     u16* __restrict__ WqT, u16* __restrict__ WkT, u16* __restrict__ WvT,
                     u16* __restrict__ WpkT, u16* __restrict__ WpqT) {
  __shared__ float t[32][33];
  const int bid = blockIdx.x, tid = threadIdx.x;
  if (bid < 5121) {
    const float* in;
    u16* out;
    int i;
    if (bid < 4096) { in = hs; out = hsb; i = bid * 256 + tid; }
    else            { in = rel; out = relb; i = (bid - 4096) * 256 + tid; }
    float4 v = ((const float4*)in)[i];
    ushort4 o;
    o.x = f2bf(v.x); o.y = f2bf(v.y); o.z = f2bf(v.z); o.w = f2bf(v.w);
    ((ushort4*)out)[i] = o;
    return;
  }
  const int tt = bid - 5121;
  const int z = tt >> 10, rem = tt & 1023;
  const int x0 = (rem & 31) * 32, y0 = (rem >> 5) * 32;
  const float* in;
  u16* out;
  switch (z) {
    case 0: in = Wq; out = WqT; break;
    case 1: in = Wk; out = WkT; break;
    case 2: in = Wv; out = WvT; break;
    case 3: in = Wpk; out = WpkT; break;
    default: in = Wpq; out = WpqT; break;
  }
  int tx = tid & 31, ty = tid >> 5;
  #pragma unroll
  for (int i = ty; i < 32; i += 8)
    t[i][tx] = in[(size_t)(y0 + i) * 1024 + x0 + tx];
  __syncthreads();
  #pragma unroll
  for (int i = ty; i < 32; i += 8)
    out[(size_t)(x0 + i) * 1024 + y0 + tx] = f2bf(t[tx][i]);
}

// ---------------- merged 5-matrix bf16 GEMM (proven BK=32 body) ----------------
// One dispatch, 912 blocks (plain order; XCD swizzle measured null in R15):
// fid<144 -> rel GEMMs (rk,rq; M=1025); else qkv GEMMs (q,k,v; M=4096).
// qkv mat 0,1 -> qout[(b*16+h)][s][d] via LDS-staged vectorized epilogue;
// mat 2 -> qout[..][d][s] (transposed V, LDS-transpose epilogue).
// rel mat -> rout + mat*1049600, layout [h][r][d].
__global__ void __launch_bounds__(256) gemm_all(
    const u16* __restrict__ hsb, const u16* __restrict__ relb,
    const u16* __restrict__ Wqkv, const u16* __restrict__ Wrel,
    const float* __restrict__ bq, const float* __restrict__ bk, const float* __restrict__ bv,
    const float* __restrict__ bpk, const float* __restrict__ bpq,
    u16* __restrict__ qout, u16* __restrict__ rout) {
  __shared__ __align__(16) u16 As[4096];
  __shared__ __align__(16) u16 Bs[4096];
  const int K = 1024;
  const int fid = blockIdx.x;
  const u16* A;
  const u16* BTm;
  const float* bias;
  int m0, n0, mat, M, is_rel;
  if (fid < 144) {
    is_rel = 1;
    const int by = fid / 9;
    m0 = (fid % 9) * 128;
    n0 = (by & 7) * 128;
    mat = by >> 3;
    A = relb;
    BTm = Wrel + (size_t)mat * 1048576;
    bias = (mat == 0) ? bpk : bpq;
    M = 1025;
  } else {
    is_rel = 0;
    const int qid = fid - 144;
    const int by = qid >> 5;
    m0 = (qid & 31) * 128;
    n0 = (by & 7) * 128;
    mat = by >> 3;
    A = hsb;
    BTm = Wqkv + (size_t)mat * 1048576;
    bias = (mat == 0) ? bq : ((mat == 1) ? bk : bv);
    M = 4096;
  }
  const int w = threadIdx.x >> 6, lane = threadIdx.x & 63;
  const int lj = lane & 15, lg = lane >> 4;
  const int wm = (w >> 1) * 64, wn = (w & 1) * 64;

  f32x4 acc[4][4] = {};

  const int chunk0 = w * 128 + lane;
  const int chunk1 = chunk0 + 64;
  int r0 = chunk0 >> 2, s0 = (chunk0 & 3) * 8;
  int r1 = chunk1 >> 2, s1 = (chunk1 & 3) * 8;
  int ar0 = m0 + r0; if (ar0 >= M) ar0 = M - 1;
  int ar1 = m0 + r1; if (ar1 >= M) ar1 = M - 1;
  const u16* ga0 = A + (size_t)ar0 * K + s0;
  const u16* ga1 = A + (size_t)ar1 * K + s1;
  const u16* gb0 = BTm + (size_t)(n0 + r0) * K + s0;
  const u16* gb1 = BTm + (size_t)(n0 + r1) * K + s1;
  u16* lA0 = As + (w * 2 + 0) * 512;
  u16* lA1 = As + (w * 2 + 1) * 512;
  u16* lB0 = Bs + (w * 2 + 0) * 512;
  u16* lB1 = Bs + (w * 2 + 1) * 512;

  for (int k0 = 0; k0 < K; k0 += 32) {
    GLL16(ga0 + k0, lA0);
    GLL16(ga1 + k0, lA1);
    GLL16(gb0 + k0, lB0);
    GLL16(gb1 + k0, lB1);
    __syncthreads();
    bf16x8 af[4], bf8[4];
    #pragma unroll
    for (int mf = 0; mf < 4; ++mf)
      af[mf] = *(const bf16x8*)(As + (wm + mf * 16 + lj) * 32 + lg * 8);
    #pragma unroll
    for (int nf = 0; nf < 4; ++nf)
      bf8[nf] = *(const bf16x8*)(Bs + (wn + nf * 16 + lj) * 32 + lg * 8);
    #pragma unroll
    for (int mf = 0; mf < 4; ++mf)
      #pragma unroll
      for (int nf = 0; nf < 4; ++nf)
        acc[mf][nf] = MFMA16(af[mf], bf8[nf], acc[mf][nf]);
    __syncthreads();
  }

  if (is_rel) {
    #pragma unroll
    for (int mf = 0; mf < 4; ++mf)
      #pragma unroll
      for (int nf = 0; nf < 4; ++nf) {
        const int j = n0 + wn + nf * 16 + lj;
        const float bj = bias[j];
        #pragma unroll
        for (int r = 0; r < 4; ++r) {
          const int i = m0 + wm + mf * 16 + lg * 4 + r;
          if (i >= M) continue;
          rout[(size_t)mat * 1049600 + (size_t)(j >> 6) * 65600 + (size_t)i * 64 + (j & 63)] =
              f2bf(acc[mf][nf][r] + bj);
        }
      }
  } else if (mat < 2) {
    // q/k: stage wave's 64(i)x16(d) subtile in LDS ([64][24] u16, 48B stride ->
    // aligned b128 reads), then 2x 16B global stores per nf (was 64 scalar 2B).
    u16* scr = (w < 2) ? (As + w * 1536) : (Bs + (w - 2) * 1536);
    const int hcol = (n0 + wn) >> 6;   // head-col component (const per wave)
    u16* qbase = qout + (size_t)mat * 4194304;
    const int prow = lane >> 1, phalf = (lane & 1) * 8;
    #pragma unroll
    for (int nf = 0; nf < 4; ++nf) {
      const float bj = bias[n0 + wn + nf * 16 + lj];
      #pragma unroll
      for (int mf = 0; mf < 4; ++mf)
        #pragma unroll
        for (int r = 0; r < 4; ++r)
          scr[(mf * 16 + lg * 4 + r) * 24 + lj] = f2bf(acc[mf][nf][r] + bj);
      // wave-internal: compiler inserts lgkmcnt waits between ds_write/ds_read
      #pragma unroll
      for (int pass = 0; pass < 2; ++pass) {
        const int row = pass * 32 + prow;
        uint4 v = *(const uint4*)(scr + row * 24 + phalf);
        const int gi = m0 + wm + row;
        u16* op = qbase + (size_t)(((gi >> 10) << 4) + hcol) * 65536 +
                  (size_t)(gi & 1023) * 64 + nf * 16 + phalf;
        *(uint4*)(op) = v;
      }
    }
  } else {
    // V: transpose each wave's 64(i)x16(j) subtile via LDS scratch, then
    // coalesced 16B global writes. As/Bs dead after final barrier; wave-private.
    u16* scr = (w < 2) ? (As + w * 1152) : (Bs + (w - 2) * 1152);
    u16* vout = qout + (size_t)2 * 4194304;
    const int row16 = lane >> 2, ch = lane & 3;
    #pragma unroll
    for (int nf = 0; nf < 4; ++nf) {
      const float bj = bias[n0 + wn + nf * 16 + lj];
      #pragma unroll
      for (int mf = 0; mf < 4; ++mf)
        #pragma unroll
        for (int r = 0; r < 4; ++r)
          scr[lj * 72 + mf * 16 + lg * 4 + r] = f2bf(acc[mf][nf][r] + bj);
      const u16* sp = scr + row16 * 72 + ch * 16;
      uint4 v0 = *(const uint4*)(sp);
      uint4 v1 = *(const uint4*)(sp + 8);
      const int gj = n0 + wn + nf * 16 + row16;
      const int gi = m0 + wm + ch * 16;
      u16* op = vout + (size_t)(((gi >> 10) << 4) + (gj >> 6)) * 65536 +
                (size_t)(gj & 63) * 1024 + (gi & 1023);
      *(uint4*)(op) = v0;
      *(uint4*)(op + 8) = v1;
    }
  }
}

// ---------------- fused disentangled attention (R11, unchanged) ----------------
__global__ void __launch_bounds__(256, 2) attn_fused(
    const u16* __restrict__ qg, const u16* __restrict__ kg, const u16* __restrict__ vtg,
    const u16* __restrict__ rkg, const u16* __restrict__ rqg,
    const float* __restrict__ mask, float* __restrict__ out) {
  __shared__ __align__(16) u16 Ks[64][64];     //  8192
  __shared__ __align__(16) u16 Ps[64][64];     //  8192
  __shared__ __align__(16) u16 RKs[128][64];   // 16384
  __shared__ __align__(16) u16 RQs[128][64];   // 16384
  __shared__ __align__(16) u16 Ts[64][128];    // 16384
  __shared__ __align__(16) u16 Us[64][128];    // 16384

  const int bx = ((blockIdx.x & 7) << 7) | (blockIdx.x >> 3);
  const int it = bx & 15, bn = bx >> 4;
  const int b = bn >> 4, n = bn & 15;
  const int i0 = it * 64;
  const int tid = threadIdx.x, w = tid >> 6, lane = tid & 63;
  const int lj = lane & 15, lg = lane >> 4;

  const u16* qh = qg + (size_t)bn * 65536;
  const u16* kh = kg + (size_t)bn * 65536;
  const u16* vth = vtg + (size_t)bn * 65536;
  const u16* rkh = rkg + (size_t)n * 65600;
  const u16* rqh = rqg + (size_t)n * 65600;
  const float* mk = mask + (size_t)b * 1024;

  const int l8 = lane >> 3, gK = (lane & 7) ^ l8;
  const u16* kb0  = kh  + (size_t)((w * 2 + 0) * 8 + l8) * 64 + gK * 8;
  const u16* kb1  = kh  + (size_t)((w * 2 + 1) * 8 + l8) * 64 + gK * 8;
  const u16* rkb0 = rkh + (size_t)((w * 4 + 0) * 8 + l8) * 64 + gK * 8;
  const u16* rkb1 = rkh + (size_t)((w * 4 + 1) * 8 + l8) * 64 + gK * 8;
  const u16* rkb2 = rkh + (size_t)((w * 4 + 2) * 8 + l8) * 64 + gK * 8;
  const u16* rkb3 = rkh + (size_t)((w * 4 + 3) * 8 + l8) * 64 + gK * 8;
  const u16* rqb0 = rqh + (size_t)((w * 4 + 0) * 8 + l8) * 64 + gK * 8;
  const u16* rqb1 = rqh + (size_t)((w * 4 + 1) * 8 + l8) * 64 + gK * 8;
  const u16* rqb2 = rqh + (size_t)((w * 4 + 2) * 8 + l8) * 64 + gK * 8;
  const u16* rqb3 = rqh + (size_t)((w * 4 + 3) * 8 + l8) * 64 + gK * 8;
  u16* ksd0 = &Ks[0][0]  + (w * 2 + 0) * 512;
  u16* ksd1 = &Ks[0][0]  + (w * 2 + 1) * 512;
  u16* rkd0 = &RKs[0][0] + (w * 4 + 0) * 512;
  u16* rkd1 = &RKs[0][0] + (w * 4 + 1) * 512;
  u16* rkd2 = &RKs[0][0] + (w * 4 + 2) * 512;
  u16* rkd3 = &RKs[0][0] + (w * 4 + 3) * 512;
  u16* rqd0 = &RQs[0][0] + (w * 4 + 0) * 512;
  u16* rqd1 = &RQs[0][0] + (w * 4 + 1) * 512;
  u16* rqd2 = &RQs[0][0] + (w * 4 + 2) * 512;
  u16* rqd3 = &RQs[0][0] + (w * 4 + 3) * 512;

#define STAGE_TILE(J0N) do { \
    const int ddn_ = i0 - (J0N) + 512; \
    int w0n_ = ddn_ - 63; w0n_ = w0n_ < 0 ? 0 : (w0n_ > 897 ? 897 : w0n_); \
    int w0qn_ = (1024 - ddn_) - 63; w0qn_ = w0qn_ < 0 ? 0 : (w0qn_ > 897 ? 897 : w0qn_); \
    GLL16(kb0 + (size_t)(J0N) * 64, ksd0); \
    GLL16(kb1 + (size_t)(J0N) * 64, ksd1); \
    GLL16(rkb0 + (size_t)w0n_ * 64, rkd0); \
    GLL16(rkb1 + (size_t)w0n_ * 64, rkd1); \
    GLL16(rkb2 + (size_t)w0n_ * 64, rkd2); \
    GLL16(rkb3 + (size_t)w0n_ * 64, rkd3); \
    GLL16(rqb0 + (size_t)w0qn_ * 64, rqd0); \
    GLL16(rqb1 + (size_t)w0qn_ * 64, rqd1); \
    GLL16(rqb2 + (size_t)w0qn_ * 64, rqd2); \
    GLL16(rqb3 + (size_t)w0qn_ * 64, rqd3); \
  } while (0)

  bf16x8 aq_all[4][2];
  #pragma unroll
  for (int f = 0; f < 4; ++f)
    #pragma unroll
    for (int k2 = 0; k2 < 2; ++k2)
      aq_all[f][k2] = *(const bf16x8*)(qh + (size_t)(i0 + f * 16 + lj) * 64 + k2 * 32 + lg * 8);
  bf16x8 aq_own[2];
  #pragma unroll
  for (int k2 = 0; k2 < 2; ++k2)
    aq_own[k2] = *(const bf16x8*)(qh + (size_t)(i0 + w * 16 + lj) * 64 + k2 * 32 + lg * 8);

  const u16* vrow[4];
  #pragma unroll
  for (int d = 0; d < 4; ++d)
    vrow[d] = vth + (size_t)(d * 16 + lj) * 1024 + lg * 8;

  const int swlj = (lj & 7) << 3;
  int baseT[4], swi[4], baseP[4];
  #pragma unroll
  for (int r = 0; r < 4; ++r) {
    const int il = w * 16 + lg * 4 + r;
    baseT[r] = il * 128;
    swi[r] = (il & 7) << 3;
    baseP[r] = il * 64;
  }
  const u16* Ts_f = &Ts[0][0];
  const u16* Us_f = &Us[0][0];
  u16* Ts_w = &Ts[0][0];
  u16* Us_w = &Us[0][0];
  u16* Ps_f = &Ps[0][0];

  float lsum[4] = {0.f, 0.f, 0.f, 0.f};
  f32x4 accO[4] = {};

  STAGE_TILE(0);

  for (int jt = 0; jt < 16; ++jt) {
    const int j0 = jt * 64;
    const int dd = i0 - j0 + 512;
    int w0 = dd - 63; w0 = w0 < 0 ? 0 : (w0 > 897 ? 897 : w0);
    int w0q = (1024 - dd) - 63; w0q = w0q < 0 ? 0 : (w0q > 897 ? 897 : w0q);

    __syncthreads();

    bf16x8 bk_all[4][2];
    #pragma unroll
    for (int f = 0; f < 4; ++f)
      #pragma unroll
      for (int k2 = 0; k2 < 2; ++k2) {
        const int kr = f * 16 + lj;
        bk_all[f][k2] = *(const bf16x8*)(&Ks[kr][SWZ(kr, k2 * 32 + lg * 8)]);
      }
    __builtin_amdgcn_s_setprio(1);
    f32x4 scc[4];
    #pragma unroll
    for (int jf = 0; jf < 4; ++jf) {
      scc[jf] = (f32x4){0.f, 0.f, 0.f, 0.f};
      #pragma unroll
      for (int k2 = 0; k2 < 2; ++k2)
        scc[jf] = MFMA16(aq_own[k2], bk_all[jf][k2], scc[jf]);
    }
    #pragma unroll
    for (int c16 = 0; c16 < 2; ++c16) {
      const int tc = w * 2 + c16;
      const int rr = tc * 16 + lj;
      bf16x8 brk[2], brq[2];
      #pragma unroll
      for (int k2 = 0; k2 < 2; ++k2) {
        brk[k2] = *(const bf16x8*)(&RKs[rr][SWZ(rr, k2 * 32 + lg * 8)]);
        brq[k2] = *(const bf16x8*)(&RQs[rr][SWZ(rr, k2 * 32 + lg * 8)]);
      }
      const int cb = (tc * 16 + lg * 4) ^ swlj;
      #pragma unroll
      for (int f = 0; f < 4; ++f) {
        f32x4 t_ = {0.f, 0.f, 0.f, 0.f};
        f32x4 u_ = {0.f, 0.f, 0.f, 0.f};
        #pragma unroll
        for (int k2 = 0; k2 < 2; ++k2) {
          t_ = MFMA16(brk[k2], aq_all[f][k2], t_);
          u_ = MFMA16(brq[k2], bk_all[f][k2], u_);
        }
        uint2 tp, up;
        tp.x = pk2bf(t_[0], t_[1]); tp.y = pk2bf(t_[2], t_[3]);
        up.x = pk2bf(u_[0], u_[1]); up.y = pk2bf(u_[2], u_[3]);
        *(uint2*)(Ts_w + (f * 16 + lj) * 128 + cb) = tp;
        *(uint2*)(Us_w + (f * 16 + lj) * 128 + cb) = up;
      }
    }
    __builtin_amdgcn_s_setprio(0);
    __syncthreads();

    if (jt < 15) STAGE_TILE(j0 + 64);

    bf16x8 vreg[8];
    #pragma unroll
    for (int jk = 0; jk < 2; ++jk)
      #pragma unroll
      for (int d = 0; d < 4; ++d)
        vreg[jk * 4 + d] = *(const bf16x8*)(vrow[d] + j0 + jk * 32);

    const int E = dd + w * 16 + lg * 4 - lj;
    const int C2 = 1024 - w0q;
    float mjs[4];
    #pragma unroll
    for (int jf = 0; jf < 4; ++jf)
      mjs[jf] = fmaf(mk[j0 + jf * 16 + lj], LOG2E, M8L2E);
    if (dd >= 63 && dd <= 961) {
      #pragma unroll
      for (int jf = 0; jf < 4; ++jf) {
        const int ubase = (jf * 16 + lj) * 128;
        #pragma unroll
        for (int r = 0; r < 4; ++r) {
          const int x1 = E + r - jf * 16;
          const float tT = bf2f(Ts_f[baseT[r] + ((x1 - w0) ^ swi[r])]);
          const float tU = bf2f(Us_f[ubase + ((C2 - x1) ^ swlj)]);
          const float p = __builtin_amdgcn_exp2f(
              fmaf(scc[jf][r] + tT + tU, SCALE_L2E, mjs[jf]));
          lsum[r] += p;
          Ps_f[baseP[r] + ((jf * 16 + lj) ^ (swi[r] & 56))] = f2bf(p);
        }
      }
    } else {
      #pragma unroll
      for (int jf = 0; jf < 4; ++jf) {
        const int ubase = (jf * 16 + lj) * 128;
        #pragma unroll
        for (int r = 0; r < 4; ++r) {
          int x1 = E + r - jf * 16;
          x1 = x1 < 0 ? 0 : (x1 > 1024 ? 1024 : x1);
          const float tT = bf2f(Ts_f[baseT[r] + ((x1 - w0) ^ swi[r])]);
          const float tU = bf2f(Us_f[ubase + ((C2 - x1) ^ swlj)]);
          const float p = __builtin_amdgcn_exp2f(
              fmaf(scc[jf][r] + tT + tU, SCALE_L2E, mjs[jf]));
          lsum[r] += p;
          Ps_f[baseP[r] + ((jf * 16 + lj) ^ (swi[r] & 56))] = f2bf(p);
        }
      }
    }
    __builtin_amdgcn_s_setprio(1);
    #pragma unroll
    for (int jk = 0; jk < 2; ++jk) {
      const int pr = w * 16 + lj;
      bf16x8 ap = *(const bf16x8*)(&Ps[pr][SWZ(pr, jk * 32 + lg * 8)]);
      #pragma unroll
      for (int d = 0; d < 4; ++d)
        accO[d] = MFMA16(ap, vreg[jk * 4 + d], accO[d]);
    }
    __builtin_amdgcn_s_setprio(0);
  }

  #pragma unroll
  for (int off = 1; off < 16; off <<= 1)
    #pragma unroll
    for (int r = 0; r < 4; ++r)
      lsum[r] += __shfl_xor(lsum[r], off);

  #pragma unroll
  for (int r = 0; r < 4; ++r) {
    const float inv = 1.f / lsum[r];
    const int i = i0 + w * 16 + lg * 4 + r;
    #pragma unroll
    for (int d = 0; d < 4; ++d)
      out[((size_t)b * 1024 + i) * 1024 + n * 64 + d * 16 + lj] = accO[d][r] * inv;
  }
#undef STAGE_TILE
}

extern "C" void kernel_launch(void* const* d_in, const int* in_sizes, int n_in,
                              void* d_out, int out_size, void* d_ws, size_t ws_size,
                              hipStream_t stream) {
  const float* hs   = (const float*)d_in[0];
  const float* mask = (const float*)d_in[1];
  const float* rel  = (const float*)d_in[2];
  const float* Wq   = (const float*)d_in[3];
  const float* bq   = (const float*)d_in[4];
  const float* Wk   = (const float*)d_in[5];
  const float* bk   = (const float*)d_in[6];
  const float* Wv   = (const float*)d_in[7];
  const float* bv   = (const float*)d_in[8];
  const float* Wpk  = (const float*)d_in[9];
  const float* bpk  = (const float*)d_in[10];
  const float* Wpq  = (const float*)d_in[11];
  const float* bpq  = (const float*)d_in[12];
  float* outp = (float*)d_out;

  u16* p = (u16*)d_ws;
  u16* hsb  = p; p += (size_t)4096 * 1024;
  u16* relb = p; p += (size_t)1025 * 1024;
  u16* WqT  = p; p += (size_t)1024 * 1024;   // WqT/WkT/WvT consecutive
  u16* WkT  = p; p += (size_t)1024 * 1024;
  u16* WvT  = p; p += (size_t)1024 * 1024;
  u16* WpkT = p; p += (size_t)1024 * 1024;   // WpkT/WpqT consecutive
  u16* WpqT = p; p += (size_t)1024 * 1024;
  u16* qws  = p; p += (size_t)4096 * 1024;   // q/k/v consecutive
  u16* kws  = p; p += (size_t)4096 * 1024;
  u16* vws  = p; p += (size_t)4096 * 1024;
  u16* rkws = p; p += (size_t)16 * 1025 * 64;  // rk/rq consecutive
  u16* rqws = p; p += (size_t)16 * 1025 * 64;
  if ((size_t)((char*)p - (char*)d_ws) > ws_size) return;  // ws too small: bail
  (void)kws; (void)rqws;

  prep<<<10241, 256, 0, stream>>>(hs, rel, Wq, Wk, Wv, Wpk, Wpq,
                                  hsb, relb, WqT, WkT, WvT, WpkT, WpqT);
  gemm_all<<<912, 256, 0, stream>>>(hsb, relb, WqT, WpkT,
                                    bq, bk, bv, bpk, bpq, qws, rkws);
  attn_fused<<<1024, 256, 0, stream>>>(qws, kws, vws, rkws, rqws, mask, outp);
}